// Round 1
// baseline (146.913 us; speedup 1.0000x reference)
//
#include <hip/hip_runtime.h>

#define EPS_BN 1e-5f
#define FDIM 512        // face feature dim
#define F4   128        // FDIM/4
#define HDIM 32

// ---------------------------------------------------------------------------
// K1: per-row face inverse norms: rn[i] = rsqrt(sum(face[i]^2) + 1e-12)
// one wave (64 lanes) per row; 512 floats = 2 float4 per lane
// ---------------------------------------------------------------------------
__global__ void k_face_norm(const float* __restrict__ face,
                            float* __restrict__ rn, int n) {
    int wave = (blockIdx.x * blockDim.x + threadIdx.x) >> 6;
    int lane = threadIdx.x & 63;
    if (wave >= n) return;
    const float4* f4 = (const float4*)face + (size_t)wave * F4;
    float4 a = f4[lane];
    float4 b = f4[lane + 64];
    float s = a.x*a.x + a.y*a.y + a.z*a.z + a.w*a.w
            + b.x*b.x + b.y*b.y + b.z*b.z + b.w*b.w;
    #pragma unroll
    for (int off = 32; off > 0; off >>= 1) s += __shfl_xor(s, off);
    if (lane == 0) rn[wave] = rsqrtf(s + 1e-12f);
}

// ---------------------------------------------------------------------------
// K2: 5-scalar reduction over x: Sx0, Sx1, Sx00, Sx01, Sx11
// (BN mean/var are exact functions of these + W1 since input dim = 2)
// ---------------------------------------------------------------------------
__global__ void k_xsums(const float* __restrict__ x,
                        float* __restrict__ xs, int n) {
    float s0=0.f, s1=0.f, s00=0.f, s01=0.f, s11=0.f;
    for (int i = blockIdx.x * blockDim.x + threadIdx.x; i < n;
         i += gridDim.x * blockDim.x) {
        float2 xv = ((const float2*)x)[i];
        s0  += xv.x;       s1  += xv.y;
        s00 += xv.x*xv.x;  s01 += xv.x*xv.y;  s11 += xv.y*xv.y;
    }
    #pragma unroll
    for (int off = 32; off > 0; off >>= 1) {
        s0  += __shfl_xor(s0,  off);
        s1  += __shfl_xor(s1,  off);
        s00 += __shfl_xor(s00, off);
        s01 += __shfl_xor(s01, off);
        s11 += __shfl_xor(s11, off);
    }
    __shared__ float red[4][5];
    int lane = threadIdx.x & 63, w = threadIdx.x >> 6;
    if (lane == 0) {
        red[w][0]=s0; red[w][1]=s1; red[w][2]=s00; red[w][3]=s01; red[w][4]=s11;
    }
    __syncthreads();
    if (threadIdx.x < 5) {
        float t = red[0][threadIdx.x] + red[1][threadIdx.x]
                + red[2][threadIdx.x] + red[3][threadIdx.x];
        atomicAdd(&xs[threadIdx.x], t);
    }
}

// ---------------------------------------------------------------------------
// K3: edge weights ew[e] = dot(face[src],face[dst]) * rn[src]*rn[dst]
//     + atomic deg[dst] += ew.  One wave per edge.
// ---------------------------------------------------------------------------
__global__ void k_edge_w(const float* __restrict__ face,
                         const int* __restrict__ src,
                         const int* __restrict__ dst,
                         const float* __restrict__ rn,
                         float* __restrict__ ew,
                         float* __restrict__ deg, int ne) {
    int e = (blockIdx.x * blockDim.x + threadIdx.x) >> 6;
    int lane = threadIdx.x & 63;
    if (e >= ne) return;
    int si = src[e], di = dst[e];
    const float4* fs = (const float4*)face + (size_t)si * F4;
    const float4* fd = (const float4*)face + (size_t)di * F4;
    float4 a0 = fs[lane],      b0 = fd[lane];
    float4 a1 = fs[lane + 64], b1 = fd[lane + 64];
    float s = a0.x*b0.x + a0.y*b0.y + a0.z*b0.z + a0.w*b0.w
            + a1.x*b1.x + a1.y*b1.y + a1.z*b1.z + a1.w*b1.w;
    #pragma unroll
    for (int off = 32; off > 0; off >>= 1) s += __shfl_xor(s, off);
    if (lane == 0) {
        float w = s * rn[si] * rn[di];
        ew[e] = w;
        atomicAdd(&deg[di], w);
    }
}

// ---------------------------------------------------------------------------
// K4: finalize fused parameters (1 block):
//   a[j]   = gamma[j] * rsqrt(var[j]+eps)
//   bsh[j] = beta[j]  - mu[j]*a[j]
//   v[k]   = (Wg @ wf)[k]
//   c      = bg.wf + b0 + bf
// ---------------------------------------------------------------------------
__global__ void k_params(const float* __restrict__ xs,
                         const float* __restrict__ W1,
                         const float* __restrict__ b1,
                         const float* __restrict__ gamma,
                         const float* __restrict__ beta,
                         const float* __restrict__ Wg,
                         const float* __restrict__ bg,
                         const float* __restrict__ wf,
                         const float* __restrict__ b0,
                         const float* __restrict__ bf,
                         float* __restrict__ params, int n) {
    int t = threadIdx.x;
    float invN = 1.0f / (float)n;
    float m0 = xs[0]*invN, m1 = xs[1]*invN;
    float c00 = xs[2]*invN - m0*m0;
    float c01 = xs[3]*invN - m0*m1;
    float c11 = xs[4]*invN - m1*m1;
    if (t < HDIM) {
        float w0j = W1[t], w1j = W1[HDIM + t];
        float mu  = m0*w0j + m1*w1j + b1[t];
        float var = c00*w0j*w0j + 2.f*c01*w0j*w1j + c11*w1j*w1j;
        float a   = gamma[t] * rsqrtf(var + EPS_BN);
        params[t]        = a;
        params[HDIM + t] = beta[t] - mu*a;
        float v = 0.f;
        for (int m = 0; m < HDIM; ++m) v += Wg[t*HDIM + m] * wf[m];
        params[2*HDIM + t] = v;
    } else if (t == HDIM) {
        float c = b0[0] + bf[0];
        for (int m = 0; m < HDIM; ++m) c += bg[m] * wf[m];
        params[3*HDIM] = c;
    }
}

// ---------------------------------------------------------------------------
// K5: per-node fused encoder + self-loop + linear score:
//   h = PReLU(a*(x@W1+b1)+bsh); emb = h@W2+b2
//   s[i] = emb.v ; deg[i] += 1 (stored back) ;
//   out[i] = emb.w0 + c + s[i]/deg[i]
// ---------------------------------------------------------------------------
__global__ __launch_bounds__(256)
void k_node(const float* __restrict__ x,
            const float* __restrict__ W1, const float* __restrict__ b1,
            const float* __restrict__ alpha,
            const float* __restrict__ W2, const float* __restrict__ b2,
            const float* __restrict__ w0,
            const float* __restrict__ params,
            float* __restrict__ deg, float* __restrict__ sarr,
            float* __restrict__ out, int n) {
    __shared__ float sW2[HDIM*HDIM];
    __shared__ float sW1[2*HDIM], sb1[HDIM], sa[HDIM], sbsh[HDIM];
    __shared__ float sv[HDIM], sw0[HDIM], sb2[HDIM];
    __shared__ float sc, salpha;
    for (int i = threadIdx.x; i < HDIM*HDIM; i += blockDim.x) sW2[i] = W2[i];
    if (threadIdx.x < 2*HDIM) sW1[threadIdx.x] = W1[threadIdx.x];
    if (threadIdx.x < HDIM) {
        sb1[threadIdx.x]  = b1[threadIdx.x];
        sa[threadIdx.x]   = params[threadIdx.x];
        sbsh[threadIdx.x] = params[HDIM + threadIdx.x];
        sv[threadIdx.x]   = params[2*HDIM + threadIdx.x];
        sw0[threadIdx.x]  = w0[threadIdx.x];
        sb2[threadIdx.x]  = b2[threadIdx.x];
    }
    if (threadIdx.x == 0) { sc = params[3*HDIM]; salpha = alpha[0]; }
    __syncthreads();
    int i = blockIdx.x * blockDim.x + threadIdx.x;
    if (i >= n) return;

    float2 xv = ((const float2*)x)[i];
    float h[HDIM];
    #pragma unroll
    for (int j = 0; j < HDIM; ++j) {
        float t = xv.x*sW1[j] + xv.y*sW1[HDIM + j] + sb1[j];
        t = sa[j]*t + sbsh[j];
        h[j] = (t >= 0.f) ? t : salpha*t;
    }
    float em[HDIM];
    #pragma unroll
    for (int k = 0; k < HDIM; ++k) em[k] = sb2[k];
    #pragma unroll
    for (int j = 0; j < HDIM; ++j) {
        float hj = h[j];
        #pragma unroll
        for (int k = 0; k < HDIM; ++k) em[k] += hj * sW2[j*HDIM + k];
    }
    float sdot = 0.f, ldot = 0.f;
    #pragma unroll
    for (int k = 0; k < HDIM; ++k) { sdot += em[k]*sv[k]; ldot += em[k]*sw0[k]; }

    float dfull = deg[i] + 1.0f;   // + self loop
    deg[i]  = dfull;               // store back: K6 uses full degree
    sarr[i] = sdot;
    out[i]  = ldot + sc + sdot / dfull;
}

// ---------------------------------------------------------------------------
// K6: edge scatter of the collapsed GCN score:
//   out[dst] += ew[e] * rsqrt(deg[src]*deg[dst]) * s[src]
// ---------------------------------------------------------------------------
__global__ void k_scatter(const int* __restrict__ src,
                          const int* __restrict__ dst,
                          const float* __restrict__ ew,
                          const float* __restrict__ deg,
                          const float* __restrict__ sarr,
                          float* __restrict__ out, int ne) {
    int e = blockIdx.x * blockDim.x + threadIdx.x;
    if (e >= ne) return;
    int si = src[e], di = dst[e];
    float w = ew[e] * rsqrtf(deg[si]*deg[di]) * sarr[si];
    atomicAdd(&out[di], w);
}

// ---------------------------------------------------------------------------
extern "C" void kernel_launch(void* const* d_in, const int* in_sizes, int n_in,
                              void* d_out, int out_size, void* d_ws, size_t ws_size,
                              hipStream_t stream) {
    const float* x     = (const float*)d_in[0];
    const int*   ei    = (const int*)  d_in[1];
    const float* face  = (const float*)d_in[2];
    const float* W1    = (const float*)d_in[3];
    const float* b1    = (const float*)d_in[4];
    const float* gamma = (const float*)d_in[5];
    const float* beta  = (const float*)d_in[6];
    const float* alpha = (const float*)d_in[7];
    const float* W2    = (const float*)d_in[8];
    const float* b2    = (const float*)d_in[9];
    const float* w0    = (const float*)d_in[10];
    const float* b0    = (const float*)d_in[11];
    const float* Wg    = (const float*)d_in[12];
    const float* bg    = (const float*)d_in[13];
    const float* wf    = (const float*)d_in[14];
    const float* bf    = (const float*)d_in[15];

    const int n  = in_sizes[0] / 2;   // 50000 nodes
    const int ne = in_sizes[1] / 2;   // 160000 edges
    const int* src = ei;
    const int* dst = ei + ne;

    float* ws     = (float*)d_ws;
    float* deg    = ws;                    // [n]
    float* xs     = ws + n;                // [8]  (5 used)
    float* params = ws + n + 8;            // [97] a,bsh,v,c
    float* rn     = ws + n + 112;          // [n]
    float* ew     = rn + n;                // [ne]
    float* sarr   = ew + ne;               // [n]
    float* out    = (float*)d_out;

    // zero the accumulators (deg + xsums are contiguous)
    hipMemsetAsync(deg, 0, (size_t)(n + 8) * sizeof(float), stream);

    k_face_norm<<<(n + 3) / 4, 256, 0, stream>>>(face, rn, n);
    k_xsums<<<256, 256, 0, stream>>>(x, xs, n);
    k_edge_w<<<(ne + 3) / 4, 256, 0, stream>>>(face, src, dst, rn, ew, deg, ne);
    k_params<<<1, 64, 0, stream>>>(xs, W1, b1, gamma, beta, Wg, bg, wf, b0, bf,
                                   params, n);
    k_node<<<(n + 255) / 256, 256, 0, stream>>>(x, W1, b1, alpha, W2, b2, w0,
                                                params, deg, sarr, out, n);
    k_scatter<<<(ne + 255) / 256, 256, 0, stream>>>(src, dst, ew, deg, sarr,
                                                    out, ne);
}

// Round 2
// 111.366 us; speedup vs baseline: 1.3192x; 1.3192x over previous
//
#include <hip/hip_runtime.h>
#include <hip/hip_fp16.h>

#define EPS_BN 1e-5f
#define FDIM 512        // face feature dim
#define F4   128        // FDIM/4
#define HDIM 32

// ---------------------------------------------------------------------------
// K1h: fused per-row normalize + fp16 convert:
//   fnorm[i,:] = (half)(face[i,:] * rsqrt(sum(face[i]^2)+1e-12))
// one wave per row; butterfly reduce so all lanes hold the sum
// ---------------------------------------------------------------------------
__global__ void k_face_norm_h(const float* __restrict__ face,
                              __half* __restrict__ fnorm, int n) {
    int wave = (blockIdx.x * blockDim.x + threadIdx.x) >> 6;
    int lane = threadIdx.x & 63;
    if (wave >= n) return;
    const float4* f4 = (const float4*)face + (size_t)wave * F4;
    float4 a = f4[lane];
    float4 b = f4[lane + 64];
    float s = a.x*a.x + a.y*a.y + a.z*a.z + a.w*a.w
            + b.x*b.x + b.y*b.y + b.z*b.z + b.w*b.w;
    #pragma unroll
    for (int off = 32; off > 0; off >>= 1) s += __shfl_xor(s, off);
    float rn = rsqrtf(s + 1e-12f);
    ushort4 ua, ub;
    ua.x = __half_as_ushort(__float2half(a.x * rn));
    ua.y = __half_as_ushort(__float2half(a.y * rn));
    ua.z = __half_as_ushort(__float2half(a.z * rn));
    ua.w = __half_as_ushort(__float2half(a.w * rn));
    ub.x = __half_as_ushort(__float2half(b.x * rn));
    ub.y = __half_as_ushort(__float2half(b.y * rn));
    ub.z = __half_as_ushort(__float2half(b.z * rn));
    ub.w = __half_as_ushort(__float2half(b.w * rn));
    __half* row = fnorm + (size_t)wave * FDIM;
    ((ushort4*)row)[lane]            = ua;   // elems 4l..4l+3
    ((ushort4*)(row + 256))[lane]    = ub;   // elems 256+4l..
}

// ---------------------------------------------------------------------------
// K3h: edge weights from fp16 pre-normalized rows:
//   ew[e] = dot(fnorm[src], fnorm[dst]);  deg[dst] += ew
// one wave per edge; one uint4 (8 halves, 16B) per lane per row
// ---------------------------------------------------------------------------
__device__ __forceinline__ float dotw(unsigned int ua, unsigned int ub) {
    __half2 ha = *(__half2*)&ua;
    __half2 hb = *(__half2*)&ub;
    float2 fa = __half22float2(ha);
    float2 fb = __half22float2(hb);
    return fa.x*fb.x + fa.y*fb.y;
}

__global__ void k_edge_w_h(const __half* __restrict__ fnorm,
                           const int* __restrict__ src,
                           const int* __restrict__ dst,
                           float* __restrict__ ew,
                           float* __restrict__ deg, int ne) {
    int e = (blockIdx.x * blockDim.x + threadIdx.x) >> 6;
    int lane = threadIdx.x & 63;
    if (e >= ne) return;
    int si = src[e], di = dst[e];
    uint4 a = ((const uint4*)(fnorm + (size_t)si * FDIM))[lane];
    uint4 b = ((const uint4*)(fnorm + (size_t)di * FDIM))[lane];
    float s = dotw(a.x, b.x) + dotw(a.y, b.y) + dotw(a.z, b.z) + dotw(a.w, b.w);
    #pragma unroll
    for (int off = 32; off > 0; off >>= 1) s += __shfl_xor(s, off);
    if (lane == 0) {
        ew[e] = s;
        atomicAdd(&deg[di], s);
    }
}

// ---------------------------------------------------------------------------
// Fallback fp32 path (used only if ws_size can't hold the fp16 copy)
// ---------------------------------------------------------------------------
__global__ void k_face_norm(const float* __restrict__ face,
                            float* __restrict__ rn, int n) {
    int wave = (blockIdx.x * blockDim.x + threadIdx.x) >> 6;
    int lane = threadIdx.x & 63;
    if (wave >= n) return;
    const float4* f4 = (const float4*)face + (size_t)wave * F4;
    float4 a = f4[lane];
    float4 b = f4[lane + 64];
    float s = a.x*a.x + a.y*a.y + a.z*a.z + a.w*a.w
            + b.x*b.x + b.y*b.y + b.z*b.z + b.w*b.w;
    #pragma unroll
    for (int off = 32; off > 0; off >>= 1) s += __shfl_xor(s, off);
    if (lane == 0) rn[wave] = rsqrtf(s + 1e-12f);
}

__global__ void k_edge_w(const float* __restrict__ face,
                         const int* __restrict__ src,
                         const int* __restrict__ dst,
                         const float* __restrict__ rn,
                         float* __restrict__ ew,
                         float* __restrict__ deg, int ne) {
    int e = (blockIdx.x * blockDim.x + threadIdx.x) >> 6;
    int lane = threadIdx.x & 63;
    if (e >= ne) return;
    int si = src[e], di = dst[e];
    const float4* fs = (const float4*)face + (size_t)si * F4;
    const float4* fd = (const float4*)face + (size_t)di * F4;
    float4 a0 = fs[lane],      b0 = fd[lane];
    float4 a1 = fs[lane + 64], b1 = fd[lane + 64];
    float s = a0.x*b0.x + a0.y*b0.y + a0.z*b0.z + a0.w*b0.w
            + a1.x*b1.x + a1.y*b1.y + a1.z*b1.z + a1.w*b1.w;
    #pragma unroll
    for (int off = 32; off > 0; off >>= 1) s += __shfl_xor(s, off);
    if (lane == 0) {
        float w = s * rn[si] * rn[di];
        ew[e] = w;
        atomicAdd(&deg[di], w);
    }
}

// ---------------------------------------------------------------------------
// K2: 5-scalar reduction over x (BN stats collapse: input dim = 2)
// ---------------------------------------------------------------------------
__global__ void k_xsums(const float* __restrict__ x,
                        float* __restrict__ xs, int n) {
    float s0=0.f, s1=0.f, s00=0.f, s01=0.f, s11=0.f;
    for (int i = blockIdx.x * blockDim.x + threadIdx.x; i < n;
         i += gridDim.x * blockDim.x) {
        float2 xv = ((const float2*)x)[i];
        s0  += xv.x;       s1  += xv.y;
        s00 += xv.x*xv.x;  s01 += xv.x*xv.y;  s11 += xv.y*xv.y;
    }
    #pragma unroll
    for (int off = 32; off > 0; off >>= 1) {
        s0  += __shfl_xor(s0,  off);
        s1  += __shfl_xor(s1,  off);
        s00 += __shfl_xor(s00, off);
        s01 += __shfl_xor(s01, off);
        s11 += __shfl_xor(s11, off);
    }
    __shared__ float red[4][5];
    int lane = threadIdx.x & 63, w = threadIdx.x >> 6;
    if (lane == 0) {
        red[w][0]=s0; red[w][1]=s1; red[w][2]=s00; red[w][3]=s01; red[w][4]=s11;
    }
    __syncthreads();
    if (threadIdx.x < 5) {
        float t = red[0][threadIdx.x] + red[1][threadIdx.x]
                + red[2][threadIdx.x] + red[3][threadIdx.x];
        atomicAdd(&xs[threadIdx.x], t);
    }
}

// ---------------------------------------------------------------------------
// K4: finalize fused parameters (1 block)
// ---------------------------------------------------------------------------
__global__ void k_params(const float* __restrict__ xs,
                         const float* __restrict__ W1,
                         const float* __restrict__ b1,
                         const float* __restrict__ gamma,
                         const float* __restrict__ beta,
                         const float* __restrict__ Wg,
                         const float* __restrict__ bg,
                         const float* __restrict__ wf,
                         const float* __restrict__ b0,
                         const float* __restrict__ bf,
                         float* __restrict__ params, int n) {
    int t = threadIdx.x;
    float invN = 1.0f / (float)n;
    float m0 = xs[0]*invN, m1 = xs[1]*invN;
    float c00 = xs[2]*invN - m0*m0;
    float c01 = xs[3]*invN - m0*m1;
    float c11 = xs[4]*invN - m1*m1;
    if (t < HDIM) {
        float w0j = W1[t], w1j = W1[HDIM + t];
        float mu  = m0*w0j + m1*w1j + b1[t];
        float var = c00*w0j*w0j + 2.f*c01*w0j*w1j + c11*w1j*w1j;
        float a   = gamma[t] * rsqrtf(var + EPS_BN);
        params[t]        = a;
        params[HDIM + t] = beta[t] - mu*a;
        float v = 0.f;
        for (int m = 0; m < HDIM; ++m) v += Wg[t*HDIM + m] * wf[m];
        params[2*HDIM + t] = v;
    } else if (t == HDIM) {
        float c = b0[0] + bf[0];
        for (int m = 0; m < HDIM; ++m) c += bg[m] * wf[m];
        params[3*HDIM] = c;
    }
}

// ---------------------------------------------------------------------------
// K5: per-node fused encoder + self-loop + linear score
// ---------------------------------------------------------------------------
__global__ __launch_bounds__(256)
void k_node(const float* __restrict__ x,
            const float* __restrict__ W1, const float* __restrict__ b1,
            const float* __restrict__ alpha,
            const float* __restrict__ W2, const float* __restrict__ b2,
            const float* __restrict__ w0,
            const float* __restrict__ params,
            float* __restrict__ deg, float* __restrict__ sarr,
            float* __restrict__ out, int n) {
    __shared__ float sW2[HDIM*HDIM];
    __shared__ float sW1[2*HDIM], sb1[HDIM], sa[HDIM], sbsh[HDIM];
    __shared__ float sv[HDIM], sw0[HDIM], sb2[HDIM];
    __shared__ float sc, salpha;
    for (int i = threadIdx.x; i < HDIM*HDIM; i += blockDim.x) sW2[i] = W2[i];
    if (threadIdx.x < 2*HDIM) sW1[threadIdx.x] = W1[threadIdx.x];
    if (threadIdx.x < HDIM) {
        sb1[threadIdx.x]  = b1[threadIdx.x];
        sa[threadIdx.x]   = params[threadIdx.x];
        sbsh[threadIdx.x] = params[HDIM + threadIdx.x];
        sv[threadIdx.x]   = params[2*HDIM + threadIdx.x];
        sw0[threadIdx.x]  = w0[threadIdx.x];
        sb2[threadIdx.x]  = b2[threadIdx.x];
    }
    if (threadIdx.x == 0) { sc = params[3*HDIM]; salpha = alpha[0]; }
    __syncthreads();
    int i = blockIdx.x * blockDim.x + threadIdx.x;
    if (i >= n) return;

    float2 xv = ((const float2*)x)[i];
    float h[HDIM];
    #pragma unroll
    for (int j = 0; j < HDIM; ++j) {
        float t = xv.x*sW1[j] + xv.y*sW1[HDIM + j] + sb1[j];
        t = sa[j]*t + sbsh[j];
        h[j] = (t >= 0.f) ? t : salpha*t;
    }
    float em[HDIM];
    #pragma unroll
    for (int k = 0; k < HDIM; ++k) em[k] = sb2[k];
    #pragma unroll
    for (int j = 0; j < HDIM; ++j) {
        float hj = h[j];
        #pragma unroll
        for (int k = 0; k < HDIM; ++k) em[k] += hj * sW2[j*HDIM + k];
    }
    float sdot = 0.f, ldot = 0.f;
    #pragma unroll
    for (int k = 0; k < HDIM; ++k) { sdot += em[k]*sv[k]; ldot += em[k]*sw0[k]; }

    float dfull = deg[i] + 1.0f;   // + self loop
    deg[i]  = dfull;               // store back: K6 uses full degree
    sarr[i] = sdot;
    out[i]  = ldot + sc + sdot / dfull;
}

// ---------------------------------------------------------------------------
// K6: edge scatter of the collapsed GCN score
// ---------------------------------------------------------------------------
__global__ void k_scatter(const int* __restrict__ src,
                          const int* __restrict__ dst,
                          const float* __restrict__ ew,
                          const float* __restrict__ deg,
                          const float* __restrict__ sarr,
                          float* __restrict__ out, int ne) {
    int e = blockIdx.x * blockDim.x + threadIdx.x;
    if (e >= ne) return;
    int si = src[e], di = dst[e];
    float w = ew[e] * rsqrtf(deg[si]*deg[di]) * sarr[si];
    atomicAdd(&out[di], w);
}

// ---------------------------------------------------------------------------
extern "C" void kernel_launch(void* const* d_in, const int* in_sizes, int n_in,
                              void* d_out, int out_size, void* d_ws, size_t ws_size,
                              hipStream_t stream) {
    const float* x     = (const float*)d_in[0];
    const int*   ei    = (const int*)  d_in[1];
    const float* face  = (const float*)d_in[2];
    const float* W1    = (const float*)d_in[3];
    const float* b1    = (const float*)d_in[4];
    const float* gamma = (const float*)d_in[5];
    const float* beta  = (const float*)d_in[6];
    const float* alpha = (const float*)d_in[7];
    const float* W2    = (const float*)d_in[8];
    const float* b2    = (const float*)d_in[9];
    const float* w0    = (const float*)d_in[10];
    const float* b0    = (const float*)d_in[11];
    const float* Wg    = (const float*)d_in[12];
    const float* bg    = (const float*)d_in[13];
    const float* wf    = (const float*)d_in[14];
    const float* bf    = (const float*)d_in[15];

    const int n  = in_sizes[0] / 2;   // 50000 nodes
    const int ne = in_sizes[1] / 2;   // 160000 edges
    const int* src = ei;
    const int* dst = ei + ne;

    // workspace layout (floats)
    float* ws     = (float*)d_ws;
    float* deg    = ws;                         // [n]
    float* xs     = ws + n;                     // [8] (5 used)
    float* params = ws + n + 8;                 // [104] (97 used)
    float* sarr   = ws + n + 112;               // [n]
    float* ew     = ws + 2*n + 112;             // [ne]
    size_t off    = (size_t)2*n + 112 + ne;     // after ew
    off = (off + 3) & ~(size_t)3;               // 16B align
    float*  rn    = ws + off;                   // [n] (fallback only)
    __half* fnorm = (__half*)(ws + off);        // [n*FDIM] halves (fp16 path)

    size_t need_f16 = (off + (size_t)n * (FDIM/2)) * sizeof(float);
    bool use_f16 = (ws_size >= need_f16);

    float* out = (float*)d_out;

    // zero accumulators (deg + xs contiguous)
    hipMemsetAsync(deg, 0, (size_t)(n + 8) * sizeof(float), stream);

    k_xsums<<<256, 256, 0, stream>>>(x, xs, n);
    k_params<<<1, 64, 0, stream>>>(xs, W1, b1, gamma, beta, Wg, bg, wf, b0, bf,
                                   params, n);

    if (use_f16) {
        k_face_norm_h<<<(n + 3) / 4, 256, 0, stream>>>(face, fnorm, n);
        k_edge_w_h<<<(ne + 3) / 4, 256, 0, stream>>>(fnorm, src, dst, ew, deg, ne);
    } else {
        k_face_norm<<<(n + 3) / 4, 256, 0, stream>>>(face, rn, n);
        k_edge_w<<<(ne + 3) / 4, 256, 0, stream>>>(face, src, dst, rn, ew, deg, ne);
    }

    k_node<<<(n + 255) / 256, 256, 0, stream>>>(x, W1, b1, alpha, W2, b2, w0,
                                                params, deg, sarr, out, n);
    k_scatter<<<(ne + 255) / 256, 256, 0, stream>>>(src, dst, ew, deg, sarr,
                                                    out, ne);
}

// Round 3
// 78.471 us; speedup vs baseline: 1.8722x; 1.4192x over previous
//
#include <hip/hip_runtime.h>

#define EPS_BN 1e-5f
#define FDIM 512        // face feature dim
#define F4   128        // FDIM/4
#define HDIM 32
#define NB_XS 64        // partial-sum blocks for xsums

// ---------------------------------------------------------------------------
// K1q: fused per-row normalize + int8 quantize (one wave per row):
//   rn = rsqrt(sum(face^2)+1e-12); m = max|face|
//   q_i = round(face_i * 127/m)   (row-normalization cancels in the ratio)
//   scale[row] = m * rn / 127     (so q_i*scale ~= normalized value)
// Also zeroes deg[row] (replaces a memset dispatch).
// ---------------------------------------------------------------------------
__global__ void k_quant(const float* __restrict__ face,
                        uint2* __restrict__ qrows,   // [n*64] : 512 B/row
                        float* __restrict__ scales,  // [n]
                        float* __restrict__ deg,     // [n] zeroed here
                        int n) {
    int row  = (blockIdx.x * blockDim.x + threadIdx.x) >> 6;
    int lane = threadIdx.x & 63;
    if (row >= n) return;
    const float4* f4 = (const float4*)face + (size_t)row * F4;
    float4 a = f4[lane];        // dims 4l .. 4l+3
    float4 b = f4[lane + 64];   // dims 256+4l .. 256+4l+3
    float ss = a.x*a.x + a.y*a.y + a.z*a.z + a.w*a.w
             + b.x*b.x + b.y*b.y + b.z*b.z + b.w*b.w;
    float mx = fmaxf(fmaxf(fmaxf(fabsf(a.x), fabsf(a.y)),
                           fmaxf(fabsf(a.z), fabsf(a.w))),
                     fmaxf(fmaxf(fabsf(b.x), fabsf(b.y)),
                           fmaxf(fabsf(b.z), fabsf(b.w))));
    #pragma unroll
    for (int off = 32; off > 0; off >>= 1) {
        ss += __shfl_xor(ss, off);
        mx  = fmaxf(mx, __shfl_xor(mx, off));
    }
    float rn = rsqrtf(ss + 1e-12f);
    float qs = (mx > 0.f) ? 127.0f / mx : 0.f;
    unsigned da =  ((unsigned)(__float2int_rn(a.x*qs) & 255))
                | (((unsigned)(__float2int_rn(a.y*qs) & 255)) << 8)
                | (((unsigned)(__float2int_rn(a.z*qs) & 255)) << 16)
                | (((unsigned)(__float2int_rn(a.w*qs) & 255)) << 24);
    unsigned db =  ((unsigned)(__float2int_rn(b.x*qs) & 255))
                | (((unsigned)(__float2int_rn(b.y*qs) & 255)) << 8)
                | (((unsigned)(__float2int_rn(b.z*qs) & 255)) << 16)
                | (((unsigned)(__float2int_rn(b.w*qs) & 255)) << 24);
    qrows[(size_t)row * 64 + lane] = make_uint2(da, db);
    if (lane == 0) {
        scales[row] = mx * rn * (1.0f / 127.0f);
        deg[row]    = 0.f;
    }
}

// ---------------------------------------------------------------------------
// K3q: edge weights from int8 rows. 2 edges per wave (32 lanes/edge),
// one uint4 (16 int8 dims) per lane per row. Exact int32 accumulation.
// ---------------------------------------------------------------------------
__device__ __forceinline__ int dot4i8(unsigned a, unsigned b) {
    int s;
    s  = (int)(signed char)(a      ) * (int)(signed char)(b      );
    s += (int)(signed char)(a >>  8) * (int)(signed char)(b >>  8);
    s += (int)(signed char)(a >> 16) * (int)(signed char)(b >> 16);
    s += (int)(signed char)(a >> 24) * (int)(signed char)(b >> 24);
    return s;
}

__global__ void k_edge_q(const uint4* __restrict__ qrows,  // [n*32]
                         const float* __restrict__ scales,
                         const int* __restrict__ src,
                         const int* __restrict__ dst,
                         float* __restrict__ ew,
                         float* __restrict__ deg, int ne) {
    int tid  = blockIdx.x * blockDim.x + threadIdx.x;
    int e    = tid >> 5;                 // 32 lanes per edge
    int lane = threadIdx.x & 31;
    if (e >= ne) return;
    int si = src[e], di = dst[e];
    uint4 a = qrows[(size_t)si * 32 + lane];
    uint4 b = qrows[(size_t)di * 32 + lane];
    int acc = dot4i8(a.x, b.x) + dot4i8(a.y, b.y)
            + dot4i8(a.z, b.z) + dot4i8(a.w, b.w);
    #pragma unroll
    for (int off = 16; off > 0; off >>= 1) acc += __shfl_xor(acc, off);
    if (lane == 0) {
        float w = (float)acc * scales[si] * scales[di];
        ew[e] = w;
        atomicAdd(&deg[di], w);
    }
}

// ---------------------------------------------------------------------------
// K2: 5-scalar reduction over x -> per-block partials (no atomics)
// ---------------------------------------------------------------------------
__global__ void k_xsums(const float* __restrict__ x,
                        float* __restrict__ part, int n) {
    float s0=0.f, s1=0.f, s00=0.f, s01=0.f, s11=0.f;
    for (int i = blockIdx.x * blockDim.x + threadIdx.x; i < n;
         i += gridDim.x * blockDim.x) {
        float2 xv = ((const float2*)x)[i];
        s0  += xv.x;       s1  += xv.y;
        s00 += xv.x*xv.x;  s01 += xv.x*xv.y;  s11 += xv.y*xv.y;
    }
    #pragma unroll
    for (int off = 32; off > 0; off >>= 1) {
        s0  += __shfl_xor(s0,  off);
        s1  += __shfl_xor(s1,  off);
        s00 += __shfl_xor(s00, off);
        s01 += __shfl_xor(s01, off);
        s11 += __shfl_xor(s11, off);
    }
    __shared__ float red[4][5];
    int lane = threadIdx.x & 63, w = threadIdx.x >> 6;
    if (lane == 0) {
        red[w][0]=s0; red[w][1]=s1; red[w][2]=s00; red[w][3]=s01; red[w][4]=s11;
    }
    __syncthreads();
    if (threadIdx.x < 5) {
        part[blockIdx.x * 5 + threadIdx.x] =
            red[0][threadIdx.x] + red[1][threadIdx.x]
          + red[2][threadIdx.x] + red[3][threadIdx.x];
    }
}

// ---------------------------------------------------------------------------
// K4: reduce partials + finalize fused parameters (1 block)
// ---------------------------------------------------------------------------
__global__ void k_params(const float* __restrict__ part,
                         const float* __restrict__ W1,
                         const float* __restrict__ b1,
                         const float* __restrict__ gamma,
                         const float* __restrict__ beta,
                         const float* __restrict__ Wg,
                         const float* __restrict__ bg,
                         const float* __restrict__ wf,
                         const float* __restrict__ b0,
                         const float* __restrict__ bf,
                         float* __restrict__ params, int n) {
    __shared__ float xsl[5];
    int t = threadIdx.x;
    if (t < 5) {
        float s = 0.f;
        for (int i = 0; i < NB_XS; ++i) s += part[i * 5 + t];
        xsl[t] = s;
    }
    __syncthreads();
    float invN = 1.0f / (float)n;
    float m0 = xsl[0]*invN, m1 = xsl[1]*invN;
    float c00 = xsl[2]*invN - m0*m0;
    float c01 = xsl[3]*invN - m0*m1;
    float c11 = xsl[4]*invN - m1*m1;
    if (t < HDIM) {
        float w0j = W1[t], w1j = W1[HDIM + t];
        float mu  = m0*w0j + m1*w1j + b1[t];
        float var = c00*w0j*w0j + 2.f*c01*w0j*w1j + c11*w1j*w1j;
        float a   = gamma[t] * rsqrtf(var + EPS_BN);
        params[t]        = a;
        params[HDIM + t] = beta[t] - mu*a;
        float v = 0.f;
        for (int m = 0; m < HDIM; ++m) v += Wg[t*HDIM + m] * wf[m];
        params[2*HDIM + t] = v;
    } else if (t == HDIM) {
        float c = b0[0] + bf[0];
        for (int m = 0; m < HDIM; ++m) c += bg[m] * wf[m];
        params[3*HDIM] = c;
    }
}

// ---------------------------------------------------------------------------
// K5: per-node fused encoder + self-loop + linear score
// ---------------------------------------------------------------------------
__global__ __launch_bounds__(256)
void k_node(const float* __restrict__ x,
            const float* __restrict__ W1, const float* __restrict__ b1,
            const float* __restrict__ alpha,
            const float* __restrict__ W2, const float* __restrict__ b2,
            const float* __restrict__ w0,
            const float* __restrict__ params,
            float* __restrict__ deg, float* __restrict__ sarr,
            float* __restrict__ out, int n) {
    __shared__ float sW2[HDIM*HDIM];
    __shared__ float sW1[2*HDIM], sb1[HDIM], sa[HDIM], sbsh[HDIM];
    __shared__ float sv[HDIM], sw0[HDIM], sb2[HDIM];
    __shared__ float sc, salpha;
    for (int i = threadIdx.x; i < HDIM*HDIM; i += blockDim.x) sW2[i] = W2[i];
    if (threadIdx.x < 2*HDIM) sW1[threadIdx.x] = W1[threadIdx.x];
    if (threadIdx.x < HDIM) {
        sb1[threadIdx.x]  = b1[threadIdx.x];
        sa[threadIdx.x]   = params[threadIdx.x];
        sbsh[threadIdx.x] = params[HDIM + threadIdx.x];
        sv[threadIdx.x]   = params[2*HDIM + threadIdx.x];
        sw0[threadIdx.x]  = w0[threadIdx.x];
        sb2[threadIdx.x]  = b2[threadIdx.x];
    }
    if (threadIdx.x == 0) { sc = params[3*HDIM]; salpha = alpha[0]; }
    __syncthreads();
    int i = blockIdx.x * blockDim.x + threadIdx.x;
    if (i >= n) return;

    float2 xv = ((const float2*)x)[i];
    float h[HDIM];
    #pragma unroll
    for (int j = 0; j < HDIM; ++j) {
        float t = xv.x*sW1[j] + xv.y*sW1[HDIM + j] + sb1[j];
        t = sa[j]*t + sbsh[j];
        h[j] = (t >= 0.f) ? t : salpha*t;
    }
    float em[HDIM];
    #pragma unroll
    for (int k = 0; k < HDIM; ++k) em[k] = sb2[k];
    #pragma unroll
    for (int j = 0; j < HDIM; ++j) {
        float hj = h[j];
        #pragma unroll
        for (int k = 0; k < HDIM; ++k) em[k] += hj * sW2[j*HDIM + k];
    }
    float sdot = 0.f, ldot = 0.f;
    #pragma unroll
    for (int k = 0; k < HDIM; ++k) { sdot += em[k]*sv[k]; ldot += em[k]*sw0[k]; }

    float dfull = deg[i] + 1.0f;   // + self loop
    deg[i]  = dfull;               // store back: K6 uses full degree
    sarr[i] = sdot;
    out[i]  = ldot + sc + sdot / dfull;
}

// ---------------------------------------------------------------------------
// K6: edge scatter of the collapsed GCN score
// ---------------------------------------------------------------------------
__global__ void k_scatter(const int* __restrict__ src,
                          const int* __restrict__ dst,
                          const float* __restrict__ ew,
                          const float* __restrict__ deg,
                          const float* __restrict__ sarr,
                          float* __restrict__ out, int ne) {
    int e = blockIdx.x * blockDim.x + threadIdx.x;
    if (e >= ne) return;
    int si = src[e], di = dst[e];
    float w = ew[e] * rsqrtf(deg[si]*deg[di]) * sarr[si];
    atomicAdd(&out[di], w);
}

// ---------------------------------------------------------------------------
extern "C" void kernel_launch(void* const* d_in, const int* in_sizes, int n_in,
                              void* d_out, int out_size, void* d_ws, size_t ws_size,
                              hipStream_t stream) {
    const float* x     = (const float*)d_in[0];
    const int*   ei    = (const int*)  d_in[1];
    const float* face  = (const float*)d_in[2];
    const float* W1    = (const float*)d_in[3];
    const float* b1    = (const float*)d_in[4];
    const float* gamma = (const float*)d_in[5];
    const float* beta  = (const float*)d_in[6];
    const float* alpha = (const float*)d_in[7];
    const float* W2    = (const float*)d_in[8];
    const float* b2    = (const float*)d_in[9];
    const float* w0    = (const float*)d_in[10];
    const float* b0    = (const float*)d_in[11];
    const float* Wg    = (const float*)d_in[12];
    const float* bg    = (const float*)d_in[13];
    const float* wf    = (const float*)d_in[14];
    const float* bf    = (const float*)d_in[15];

    const int n  = in_sizes[0] / 2;   // 50000 nodes
    const int ne = in_sizes[1] / 2;   // 160000 edges
    const int* src = ei;
    const int* dst = ei + ne;

    // workspace layout (floats). qrows first for 16B alignment.
    float* ws     = (float*)d_ws;
    uint2* qrows  = (uint2*)ws;                       // n*512 B  = n*128 floats
    float* after  = ws + (size_t)n * 128;
    float* deg    = after;                            // [n]
    float* scales = after + n;                        // [n]
    float* sarr   = after + 2*(size_t)n;              // [n]
    float* ew     = after + 3*(size_t)n;              // [ne]
    float* part   = after + 3*(size_t)n + ne;         // [NB_XS*5]
    float* params = part + NB_XS*5 + 3;               // [104]
    float* out    = (float*)d_out;

    k_quant <<<(n + 3) / 4, 256, 0, stream>>>(face, qrows, scales, deg, n);
    k_xsums <<<NB_XS, 256, 0, stream>>>(x, part, n);
    k_params<<<1, 64, 0, stream>>>(part, W1, b1, gamma, beta, Wg, bg, wf,
                                   b0, bf, params, n);
    k_edge_q<<<(ne + 7) / 8, 256, 0, stream>>>((const uint4*)qrows, scales,
                                               src, dst, ew, deg, ne);
    k_node  <<<(n + 255) / 256, 256, 0, stream>>>(x, W1, b1, alpha, W2, b2, w0,
                                                  params, deg, sarr, out, n);
    k_scatter<<<(ne + 255) / 256, 256, 0, stream>>>(src, dst, ew, deg, sarr,
                                                    out, ne);
}

// Round 4
// 66.460 us; speedup vs baseline: 2.2105x; 1.1807x over previous
//
#include <hip/hip_runtime.h>

#define EPS_BN 1e-5f
#define FDIM 512        // face feature dim
#define F4   128        // FDIM/4
#define HDIM 32
#define NB_XS 64        // partial-sum blocks for xsums

// ---------------------------------------------------------------------------
__device__ __forceinline__ int dot4i8(unsigned a, unsigned b) {
#if __has_builtin(__builtin_amdgcn_sdot4)
    return __builtin_amdgcn_sdot4((int)a, (int)b, 0, false);
#else
    int s;
    s  = (int)(signed char)(a      ) * (int)(signed char)(b      );
    s += (int)(signed char)(a >>  8) * (int)(signed char)(b >>  8);
    s += (int)(signed char)(a >> 16) * (int)(signed char)(b >> 16);
    s += (int)(signed char)(a >> 24) * (int)(signed char)(b >> 24);
    return s;
#endif
}

// ---------------------------------------------------------------------------
// K_A: blocks [0,qb): per-row normalize+int8 quantize (+zero deg)
//      blocks [qb,qb+NB_XS): 5-scalar partial sums over x
// ---------------------------------------------------------------------------
__global__ __launch_bounds__(256)
void k_prep(const float* __restrict__ face,
            const float* __restrict__ x,
            uint2* __restrict__ qrows,   // [n*64] : 512 B/row
            float* __restrict__ scales,  // [n]
            float* __restrict__ deg,     // [n] zeroed here
            float* __restrict__ part,    // [NB_XS*5]
            int n, int qb) {
    __shared__ float red[4][5];
    if ((int)blockIdx.x < qb) {
        // ---- quant path: one wave per row ----
        int row  = (int)((blockIdx.x * 256 + threadIdx.x) >> 6);
        int lane = threadIdx.x & 63;
        if (row >= n) return;
        const float4* f4 = (const float4*)face + (size_t)row * F4;
        float4 a = f4[lane];
        float4 b = f4[lane + 64];
        float ss = a.x*a.x + a.y*a.y + a.z*a.z + a.w*a.w
                 + b.x*b.x + b.y*b.y + b.z*b.z + b.w*b.w;
        float mx = fmaxf(fmaxf(fmaxf(fabsf(a.x), fabsf(a.y)),
                               fmaxf(fabsf(a.z), fabsf(a.w))),
                         fmaxf(fmaxf(fabsf(b.x), fabsf(b.y)),
                               fmaxf(fabsf(b.z), fabsf(b.w))));
        #pragma unroll
        for (int off = 32; off > 0; off >>= 1) {
            ss += __shfl_xor(ss, off);
            mx  = fmaxf(mx, __shfl_xor(mx, off));
        }
        float rn = rsqrtf(ss + 1e-12f);
        float qs = (mx > 0.f) ? 127.0f / mx : 0.f;
        unsigned da =  ((unsigned)(__float2int_rn(a.x*qs) & 255))
                    | (((unsigned)(__float2int_rn(a.y*qs) & 255)) << 8)
                    | (((unsigned)(__float2int_rn(a.z*qs) & 255)) << 16)
                    | (((unsigned)(__float2int_rn(a.w*qs) & 255)) << 24);
        unsigned db =  ((unsigned)(__float2int_rn(b.x*qs) & 255))
                    | (((unsigned)(__float2int_rn(b.y*qs) & 255)) << 8)
                    | (((unsigned)(__float2int_rn(b.z*qs) & 255)) << 16)
                    | (((unsigned)(__float2int_rn(b.w*qs) & 255)) << 24);
        qrows[(size_t)row * 64 + lane] = make_uint2(da, db);
        if (lane == 0) {
            scales[row] = mx * rn * (1.0f / 127.0f);
            deg[row]    = 0.f;
        }
    } else {
        // ---- xsums path ----
        int bid = (int)blockIdx.x - qb;
        float s0=0.f, s1=0.f, s00=0.f, s01=0.f, s11=0.f;
        for (int i = bid * 256 + threadIdx.x; i < n; i += NB_XS * 256) {
            float2 xv = ((const float2*)x)[i];
            s0  += xv.x;       s1  += xv.y;
            s00 += xv.x*xv.x;  s01 += xv.x*xv.y;  s11 += xv.y*xv.y;
        }
        #pragma unroll
        for (int off = 32; off > 0; off >>= 1) {
            s0  += __shfl_xor(s0,  off);
            s1  += __shfl_xor(s1,  off);
            s00 += __shfl_xor(s00, off);
            s01 += __shfl_xor(s01, off);
            s11 += __shfl_xor(s11, off);
        }
        int lane = threadIdx.x & 63, w = threadIdx.x >> 6;
        if (lane == 0) {
            red[w][0]=s0; red[w][1]=s1; red[w][2]=s00; red[w][3]=s01; red[w][4]=s11;
        }
        __syncthreads();
        if (threadIdx.x < 5) {
            part[bid * 5 + threadIdx.x] =
                red[0][threadIdx.x] + red[1][threadIdx.x]
              + red[2][threadIdx.x] + red[3][threadIdx.x];
        }
    }
}

// ---------------------------------------------------------------------------
// K_B: reduce partials + finalize fused parameters (1 block, 64 threads)
//   params: [0,32) a   [32,64) bsh   [64,96) v = Wg@wf   [96] c
// ---------------------------------------------------------------------------
__global__ void k_params(const float* __restrict__ part,
                         const float* __restrict__ W1,
                         const float* __restrict__ b1,
                         const float* __restrict__ gamma,
                         const float* __restrict__ beta,
                         const float* __restrict__ Wg,
                         const float* __restrict__ bg,
                         const float* __restrict__ wf,
                         const float* __restrict__ b0,
                         const float* __restrict__ bf,
                         float* __restrict__ params, int n) {
    __shared__ float xsl[5];
    int t = threadIdx.x;
    if (t < 5) {
        float s = 0.f;
        for (int i = 0; i < NB_XS; ++i) s += part[i * 5 + t];
        xsl[t] = s;
    }
    __syncthreads();
    float invN = 1.0f / (float)n;
    float m0 = xsl[0]*invN, m1 = xsl[1]*invN;
    float c00 = xsl[2]*invN - m0*m0;
    float c01 = xsl[3]*invN - m0*m1;
    float c11 = xsl[4]*invN - m1*m1;
    if (t < HDIM) {
        float w0j = W1[t], w1j = W1[HDIM + t];
        float mu  = m0*w0j + m1*w1j + b1[t];
        float var = c00*w0j*w0j + 2.f*c01*w0j*w1j + c11*w1j*w1j;
        float a   = gamma[t] * rsqrtf(var + EPS_BN);
        params[t]        = a;
        params[HDIM + t] = beta[t] - mu*a;
        float v = 0.f;
        for (int m = 0; m < HDIM; ++m) v += Wg[t*HDIM + m] * wf[m];
        params[2*HDIM + t] = v;
    } else if (t == HDIM) {
        float c = b0[0] + bf[0];
        for (int m = 0; m < HDIM; ++m) c += bg[m] * wf[m];
        params[3*HDIM] = c;
    }
}

// ---------------------------------------------------------------------------
// K_C: blocks [0,nbn): node  — emb, sarr[i]=emb.v, out[i]=emb.w0+c (base)
//      blocks [nbn,..): edge — ew[e]=idot*s*s, deg[dst]+=ew
// Edge: 16 lanes per edge, 4 independent 16B gathers in flight per lane.
// ---------------------------------------------------------------------------
__global__ __launch_bounds__(256)
void k_main(const float* __restrict__ x,
            const float* __restrict__ W1, const float* __restrict__ b1,
            const float* __restrict__ alpha,
            const float* __restrict__ W2, const float* __restrict__ b2,
            const float* __restrict__ w0,
            const float* __restrict__ params,
            const uint4* __restrict__ qrows,
            const float* __restrict__ scales,
            const int* __restrict__ src,
            const int* __restrict__ dst,
            float* __restrict__ ew,
            float* __restrict__ deg,
            float* __restrict__ sarr,
            float* __restrict__ out,
            int n, int ne, int nbn) {
    __shared__ float sW2[HDIM*HDIM];
    __shared__ float sW1[2*HDIM], sb1[HDIM], sa[HDIM], sbsh[HDIM];
    __shared__ float sv[HDIM], sw0[HDIM], sb2[HDIM];
    __shared__ float sc, salpha;

    if ((int)blockIdx.x < nbn) {
        // ---- node path ----
        for (int i = threadIdx.x; i < HDIM*HDIM; i += blockDim.x) sW2[i] = W2[i];
        if (threadIdx.x < 2*HDIM) sW1[threadIdx.x] = W1[threadIdx.x];
        if (threadIdx.x < HDIM) {
            sb1[threadIdx.x]  = b1[threadIdx.x];
            sa[threadIdx.x]   = params[threadIdx.x];
            sbsh[threadIdx.x] = params[HDIM + threadIdx.x];
            sv[threadIdx.x]   = params[2*HDIM + threadIdx.x];
            sw0[threadIdx.x]  = w0[threadIdx.x];
            sb2[threadIdx.x]  = b2[threadIdx.x];
        }
        if (threadIdx.x == 0) { sc = params[3*HDIM]; salpha = alpha[0]; }
        __syncthreads();
        int i = blockIdx.x * blockDim.x + threadIdx.x;
        if (i >= n) return;

        float2 xv = ((const float2*)x)[i];
        float h[HDIM];
        #pragma unroll
        for (int j = 0; j < HDIM; ++j) {
            float t = xv.x*sW1[j] + xv.y*sW1[HDIM + j] + sb1[j];
            t = sa[j]*t + sbsh[j];
            h[j] = (t >= 0.f) ? t : salpha*t;
        }
        float em[HDIM];
        #pragma unroll
        for (int k = 0; k < HDIM; ++k) em[k] = sb2[k];
        #pragma unroll
        for (int j = 0; j < HDIM; ++j) {
            float hj = h[j];
            #pragma unroll
            for (int k = 0; k < HDIM; ++k) em[k] += hj * sW2[j*HDIM + k];
        }
        float sdot = 0.f, ldot = 0.f;
        #pragma unroll
        for (int k = 0; k < HDIM; ++k) { sdot += em[k]*sv[k]; ldot += em[k]*sw0[k]; }
        sarr[i] = sdot;
        out[i]  = ldot + sc;   // base; self-loop + edge terms added in K_D
    } else {
        // ---- edge path: 16 lanes per edge ----
        int e  = ((int)blockIdx.x - nbn) * 16 + (int)(threadIdx.x >> 4);
        int gl = threadIdx.x & 15;
        if (e >= ne) return;
        int si = src[e], di = dst[e];
        const uint4* rs = qrows + (size_t)si * 32;
        const uint4* rd = qrows + (size_t)di * 32;
        uint4 a0 = rs[gl], a1 = rs[gl + 16];
        uint4 b0 = rd[gl], b1 = rd[gl + 16];
        int acc = dot4i8(a0.x, b0.x) + dot4i8(a0.y, b0.y)
                + dot4i8(a0.z, b0.z) + dot4i8(a0.w, b0.w)
                + dot4i8(a1.x, b1.x) + dot4i8(a1.y, b1.y)
                + dot4i8(a1.z, b1.z) + dot4i8(a1.w, b1.w);
        #pragma unroll
        for (int off = 8; off > 0; off >>= 1) acc += __shfl_xor(acc, off);
        if (gl == 0) {
            float w = (float)acc * scales[si] * scales[di];
            ew[e] = w;
            atomicAdd(&deg[di], w);
        }
    }
}

// ---------------------------------------------------------------------------
// K_D: t<ne : out[dst] += ew*rsqrt((deg_s+1)(deg_d+1))*sarr[src]
//      t>=ne: out[i]   += sarr[i]/(deg[i]+1)      (self-loop)
// ---------------------------------------------------------------------------
__global__ void k_finish(const int* __restrict__ src,
                         const int* __restrict__ dst,
                         const float* __restrict__ ew,
                         const float* __restrict__ deg,
                         const float* __restrict__ sarr,
                         float* __restrict__ out, int ne, int n) {
    int t = blockIdx.x * blockDim.x + threadIdx.x;
    if (t < ne) {
        int si = src[t], di = dst[t];
        float w = ew[t] * rsqrtf((deg[si] + 1.f) * (deg[di] + 1.f)) * sarr[si];
        atomicAdd(&out[di], w);
    } else if (t < ne + n) {
        int i = t - ne;
        atomicAdd(&out[i], sarr[i] / (deg[i] + 1.f));
    }
}

// ---------------------------------------------------------------------------
extern "C" void kernel_launch(void* const* d_in, const int* in_sizes, int n_in,
                              void* d_out, int out_size, void* d_ws, size_t ws_size,
                              hipStream_t stream) {
    const float* x     = (const float*)d_in[0];
    const int*   ei    = (const int*)  d_in[1];
    const float* face  = (const float*)d_in[2];
    const float* W1    = (const float*)d_in[3];
    const float* b1    = (const float*)d_in[4];
    const float* gamma = (const float*)d_in[5];
    const float* beta  = (const float*)d_in[6];
    const float* alpha = (const float*)d_in[7];
    const float* W2    = (const float*)d_in[8];
    const float* b2    = (const float*)d_in[9];
    const float* w0    = (const float*)d_in[10];
    const float* b0    = (const float*)d_in[11];
    const float* Wg    = (const float*)d_in[12];
    const float* bg    = (const float*)d_in[13];
    const float* wf    = (const float*)d_in[14];
    const float* bf    = (const float*)d_in[15];

    const int n  = in_sizes[0] / 2;   // 50000 nodes
    const int ne = in_sizes[1] / 2;   // 160000 edges
    const int* src = ei;
    const int* dst = ei + ne;

    // workspace layout (floats). qrows first for 16B alignment.
    float* ws     = (float*)d_ws;
    uint2* qrows  = (uint2*)ws;                       // n*512 B = n*128 floats
    float* after  = ws + (size_t)n * 128;
    float* deg    = after;                            // [n]
    float* scales = after + n;                        // [n]
    float* sarr   = after + 2*(size_t)n;              // [n]
    float* ew     = after + 3*(size_t)n;              // [ne]
    float* part   = after + 3*(size_t)n + ne;         // [NB_XS*5]
    float* params = part + NB_XS*5 + 3;               // [104]
    float* out    = (float*)d_out;

    const int qb  = (n + 3) / 4;          // quant blocks (4 rows/block)
    const int nbn = (n + 255) / 256;      // node blocks
    const int ebk = (ne + 15) / 16;       // edge blocks (16 edges/block)

    k_prep  <<<qb + NB_XS, 256, 0, stream>>>(face, x, qrows, scales, deg,
                                             part, n, qb);
    k_params<<<1, 64, 0, stream>>>(part, W1, b1, gamma, beta, Wg, bg, wf,
                                   b0, bf, params, n);
    k_main  <<<nbn + ebk, 256, 0, stream>>>(x, W1, b1, alpha, W2, b2, w0,
                                            params, (const uint4*)qrows,
                                            scales, src, dst, ew, deg, sarr,
                                            out, n, ne, nbn);
    k_finish<<<(ne + n + 255) / 256, 256, 0, stream>>>(src, dst, ew, deg,
                                                       sarr, out, ne, n);
}